// Round 4
// baseline (296.734 us; speedup 1.0000x reference)
//
#include <hip/hip_runtime.h>
#include <hip/hip_bf16.h>

// Problem constants
#define Bc 8
#define Tc 2048
#define Ec 256
#define Hc 2
#define HDc 128
#define Mrows (Bc*Tc)          // 16384
#define M2c 134

using bfx8  = __attribute__((ext_vector_type(8))) __bf16;
using f32x4 = __attribute__((ext_vector_type(4))) float;

__device__ __forceinline__ void gll16(const __bf16* g, __bf16* lds) {
    __builtin_amdgcn_global_load_lds(
        (const __attribute__((address_space(1))) unsigned int*)g,
        (__attribute__((address_space(3))) unsigned int*)lds, 16, 0, 0);
}

// ---------------- prep: convert weights to bf16, zero embsum ----------------
__global__ __launch_bounds__(256) void prep_k(const float* attn_w, const float* apw,
                                              const float* fcw, const float* mpw,
                                              __bf16* wb, float* embsum) {
    int i = blockIdx.x * 256 + threadIdx.x;
    if (i < 2048) embsum[i] = 0.f;
    if (i < 196608)       wb[i] = (__bf16)attn_w[i];
    else if (i < 262144)  wb[i] = (__bf16)apw[i - 196608];
    else if (i < 393216)  wb[i] = (__bf16)fcw[i - 262144];
    else if (i < 524288)  wb[i] = (__bf16)mpw[i - 393216];
}

// ---------------- embed + relu + LN1 ----------------
__global__ __launch_bounds__(256) void embed_ln_k(const float* X, const float* wpe,
                                                  const float* g, const float* bb,
                                                  float* xres, __bf16* hb) {
    int m = blockIdx.x;
    int t = m & (Tc - 1);
    int e = threadIdx.x;
    float v = X[(size_t)m * Ec + e] + wpe[(size_t)t * Ec + e] + wpe[(size_t)(t >= 1024) * Ec + e];
    v = fmaxf(v, 0.f);
    xres[(size_t)m * Ec + e] = v;
    float s1 = v, s2 = v * v;
    #pragma unroll
    for (int o = 32; o; o >>= 1) { s1 += __shfl_xor(s1, o, 64); s2 += __shfl_xor(s2, o, 64); }
    __shared__ float a1[4], a2[4];
    int w = threadIdx.x >> 6;
    if ((threadIdx.x & 63) == 0) { a1[w] = s1; a2[w] = s2; }
    __syncthreads();
    float m1 = (a1[0] + a1[1] + a1[2] + a1[3]) * (1.f / 256.f);
    float m2 = (a2[0] + a2[1] + a2[2] + a2[3]) * (1.f / 256.f);
    float var = m2 - m1 * m1;
    float r = rsqrtf(var + 1e-5f);
    hb[(size_t)m * Ec + e] = (__bf16)((v - m1) * r * g[e] + bb[e]);
}

// ---------------- generic LN (f32 in -> bf16 out, optional post-relu) ----------------
__global__ __launch_bounds__(256) void ln_k(const float* in, const float* g, const float* bb,
                                            __bf16* outb, int relu_after) {
    int m = blockIdx.x;
    int e = threadIdx.x;
    float v = in[(size_t)m * Ec + e];
    float s1 = v, s2 = v * v;
    #pragma unroll
    for (int o = 32; o; o >>= 1) { s1 += __shfl_xor(s1, o, 64); s2 += __shfl_xor(s2, o, 64); }
    __shared__ float a1[4], a2[4];
    int w = threadIdx.x >> 6;
    if ((threadIdx.x & 63) == 0) { a1[w] = s1; a2[w] = s2; }
    __syncthreads();
    float m1 = (a1[0] + a1[1] + a1[2] + a1[3]) * (1.f / 256.f);
    float m2 = (a2[0] + a2[1] + a2[2] + a2[3]) * (1.f / 256.f);
    float r = rsqrtf(m2 - m1 * m1 + 1e-5f);
    float o = (v - m1) * r * g[e] + bb[e];
    if (relu_after) o = fmaxf(o, 0.f);
    outb[(size_t)m * Ec + e] = (__bf16)o;
}

// ---------------- B^T GEMM: C[m,n] = sum_k A[m,k]*Bw[n,k] (+ epilogue) ----------------
template <int EPI>
__global__ __launch_bounds__(256) void gemm_bt(const __bf16* __restrict__ A,
                                               const __bf16* __restrict__ Bw,
                                               const float* __restrict__ bias,
                                               int N, int K,
                                               const float* __restrict__ resid,
                                               float* __restrict__ outf,
                                               __bf16* __restrict__ outb,
                                               __bf16* __restrict__ Qb,
                                               __bf16* __restrict__ Kb,
                                               __bf16* __restrict__ Vb) {
    __shared__ __bf16 As[128 * 64];
    __shared__ __bf16 Bs[128 * 64];
    const int tid = threadIdx.x, w = tid >> 6, l = tid & 63;
    const int m0 = blockIdx.y * 128, n0 = blockIdx.x * 128;
    const int wr = w >> 1, wc = w & 1;
    const int quad = l >> 4, col15 = l & 15;

    f32x4 acc[4][4];
    f32x4 zz = {0.f, 0.f, 0.f, 0.f};
    #pragma unroll
    for (int i = 0; i < 4; i++)
        #pragma unroll
        for (int j = 0; j < 4; j++) acc[i][j] = zz;

    const int lrow = l >> 3;     // row within 1KB chunk (8 rows of 128B)
    const int pbs  = l & 7;      // physical 16B block within row

    for (int kb = 0; kb < K; kb += 64) {
        #pragma unroll
        for (int it = 0; it < 4; it++) {
            int chunk = w * 4 + it;
            int row = chunk * 8 + lrow;
            int lb = pbs ^ (row & 7);
            gll16(A  + (size_t)(m0 + row) * K + kb + lb * 8, As + chunk * 512);
            gll16(Bw + (size_t)(n0 + row) * K + kb + lb * 8, Bs + chunk * 512);
        }
        __syncthreads();
        #pragma unroll
        for (int ks = 0; ks < 2; ks++) {
            bfx8 af[4], bfr[4];
            #pragma unroll
            for (int rt = 0; rt < 4; rt++) {
                int row = wr * 64 + rt * 16 + col15;
                int pb = (ks * 4 + quad) ^ (row & 7);
                af[rt] = *(const bfx8*)(As + row * 64 + pb * 8);
            }
            #pragma unroll
            for (int ct = 0; ct < 4; ct++) {
                int row = wc * 64 + ct * 16 + col15;
                int pb = (ks * 4 + quad) ^ (row & 7);
                bfr[ct] = *(const bfx8*)(Bs + row * 64 + pb * 8);
            }
            #pragma unroll
            for (int rt = 0; rt < 4; rt++)
                #pragma unroll
                for (int ct = 0; ct < 4; ct++)
                    acc[rt][ct] = __builtin_amdgcn_mfma_f32_16x16x32_bf16(af[rt], bfr[ct], acc[rt][ct], 0, 0, 0);
        }
        __syncthreads();
    }

    #pragma unroll
    for (int rt = 0; rt < 4; rt++)
        #pragma unroll
        for (int ct = 0; ct < 4; ct++) {
            int mgb = m0 + wr * 64 + rt * 16 + quad * 4;
            int ng  = n0 + wc * 64 + ct * 16 + col15;
            float bsv = bias[ng];
            #pragma unroll
            for (int r = 0; r < 4; r++) {
                float val = acc[rt][ct][r] + bsv;
                int mg = mgb + r;
                if constexpr (EPI == 0) {
                    val = fmaxf(val, 0.f);
                    int sel = ng >> 8;
                    int hh = (ng >> 7) & 1;
                    int d = ng & 127;
                    int bb = mg >> 11, tt = mg & (Tc - 1);
                    size_t idx = ((size_t)((bb * 2 + hh) * Tc + tt)) * HDc + d;
                    __bf16 bv = (__bf16)val;
                    if (sel == 0) Qb[idx] = bv;
                    else if (sel == 1) Kb[idx] = bv;
                    else Vb[idx] = bv;
                } else if constexpr (EPI == 1) {
                    outf[(size_t)mg * 256 + ng] = resid[(size_t)mg * 256 + ng] + val;
                } else if constexpr (EPI == 2) {
                    outb[(size_t)mg * 512 + ng] = (__bf16)fmaxf(val, 0.f);
                } else {
                    outf[(size_t)mg * 256 + ng] = fmaxf(resid[(size_t)mg * 256 + ng] + val, 0.f);
                }
            }
        }
}

// ---------------- transpose V -> Vt[bh][d][t] ----------------
__global__ __launch_bounds__(256) void transpose_v(const unsigned short* Vb, unsigned short* Vt) {
    __shared__ unsigned short tile[64][66];
    int kt = blockIdx.x, dt = blockIdx.y, bh = blockIdx.z;
    int tid = threadIdx.x;
    int k0 = kt * 64, d0 = dt * 64;
    int rr = tid >> 4, cc = (tid & 15) * 4;
    #pragma unroll
    for (int p = 0; p < 4; p++) {
        int k = p * 16 + rr;
        const unsigned short* src = Vb + ((size_t)(bh * Tc + k0 + k)) * HDc + d0 + cc;
        ushort4 vv = *(const ushort4*)src;
        tile[k][cc] = vv.x; tile[k][cc + 1] = vv.y; tile[k][cc + 2] = vv.z; tile[k][cc + 3] = vv.w;
    }
    __syncthreads();
    #pragma unroll
    for (int p = 0; p < 4; p++) {
        int d = p * 16 + rr;
        unsigned short* dst = Vt + ((size_t)(bh * HDc + d0 + d)) * Tc + k0 + cc;
        ushort4 ov;
        ov.x = tile[cc][d]; ov.y = tile[cc + 1][d]; ov.z = tile[cc + 2][d]; ov.w = tile[cc + 3][d];
        *(ushort4*)dst = ov;
    }
}

// ---------------- causal relu attention ----------------
// Y[q,d] = (1/sqrt(HD)) * sum_{k<=q} relu(Q[q]·K[k]) V[k,d]
__global__ __launch_bounds__(256) void attn_k(const __bf16* __restrict__ Qb,
                                              const __bf16* __restrict__ Kb,
                                              const __bf16* __restrict__ Vt,
                                              __bf16* __restrict__ Yout) {
    __shared__ __bf16 Ks[128 * 128];   // also holds staged Q (first 16KB), then S
    __shared__ __bf16 Vts[128 * 128];
    __bf16* Ss = Ks;
    int qb = blockIdx.x, bh = blockIdx.y;
    int tid = threadIdx.x, w = tid >> 6, l = tid & 63;
    int Q0 = qb * 64;
    int quad = l >> 4, col15 = l & 15;
    int lrow = l >> 4, pbs = l & 15;   // staging: 4 rows of 256B per 1KB chunk

    // stage Q block (64 rows x 128) into Ks[0:8192]
    #pragma unroll
    for (int it = 0; it < 4; it++) {
        int chunk = w * 4 + it;
        int row = chunk * 4 + lrow;
        int lb = pbs ^ (row & 7);
        gll16(Qb + ((size_t)(bh * Tc + Q0 + row)) * HDc + lb * 8, Ks + chunk * 512);
    }
    __syncthreads();
    bfx8 qf[4];
    #pragma unroll
    for (int ks = 0; ks < 4; ks++) {
        int row = w * 16 + col15;
        int pb = (ks * 4 + quad) ^ (row & 7);
        qf[ks] = *(const bfx8*)(Ks + row * 128 + pb * 8);
    }

    f32x4 zz = {0.f, 0.f, 0.f, 0.f};
    f32x4 yacc[8];
    #pragma unroll
    for (int i = 0; i < 8; i++) yacc[i] = zz;

    int nkt = (qb >> 1) + 1;
    for (int kt = 0; kt < nkt; kt++) {
        __syncthreads();  // protect Ks/Ss/Vts from previous iteration readers
        #pragma unroll
        for (int it = 0; it < 8; it++) {
            int chunk = w * 8 + it;
            int row = chunk * 4 + lrow;
            int lb = pbs ^ (row & 7);
            gll16(Kb + ((size_t)(bh * Tc + kt * 128 + row)) * HDc + lb * 8, Ks + chunk * 512);
            gll16(Vt + ((size_t)(bh * HDc + row)) * Tc + kt * 128 + lb * 8, Vts + chunk * 512);
        }
        __syncthreads();

        // S = Q K^T  (64x128 per WG; wave w owns rows w*16..+16)
        f32x4 sacc[8];
        #pragma unroll
        for (int i = 0; i < 8; i++) sacc[i] = zz;
        #pragma unroll
        for (int ks = 0; ks < 4; ks++) {
            bfx8 kf[8];
            #pragma unroll
            for (int ct = 0; ct < 8; ct++) {
                int row = ct * 16 + col15;
                int pb = (ks * 4 + quad) ^ (row & 7);
                kf[ct] = *(const bfx8*)(Ks + row * 128 + pb * 8);
            }
            #pragma unroll
            for (int ct = 0; ct < 8; ct++)
                sacc[ct] = __builtin_amdgcn_mfma_f32_16x16x32_bf16(qf[ks], kf[ct], sacc[ct], 0, 0, 0);
        }
        __syncthreads();  // everyone done reading Ks

        // relu + causal mask, write S (bf16, swizzled) into Ss
        #pragma unroll
        for (int ct = 0; ct < 8; ct++) {
            int kl = ct * 16 + col15;
            int kg = kt * 128 + kl;
            int blk = kl >> 3, off = kl & 7;
            #pragma unroll
            for (int r = 0; r < 4; r++) {
                int qlw = w * 16 + quad * 4 + r;
                int qg = Q0 + qlw;
                float val = (kg <= qg) ? fmaxf(sacc[ct][r], 0.f) : 0.f;
                int pb = blk ^ (qlw & 7);
                Ss[qlw * 128 + pb * 8 + off] = (__bf16)val;
            }
        }
        __syncthreads();

        // Y += S * V   (B-operand from Vt tile)
        #pragma unroll
        for (int ks = 0; ks < 4; ks++) {
            int rowS = w * 16 + col15;
            int pbS = (ks * 4 + quad) ^ (rowS & 7);
            bfx8 sf = *(const bfx8*)(Ss + rowS * 128 + pbS * 8);
            #pragma unroll
            for (int dt = 0; dt < 8; dt++) {
                int rowV = dt * 16 + col15;
                int pbV = (ks * 4 + quad) ^ (rowV & 7);
                bfx8 vf = *(const bfx8*)(Vts + rowV * 128 + pbV * 8);
                yacc[dt] = __builtin_amdgcn_mfma_f32_16x16x32_bf16(sf, vf, yacc[dt], 0, 0, 0);
            }
        }
    }

    int b = bh >> 1, h = bh & 1;
    const float sc = 0.08838834764831845f;  // 1/sqrt(128)
    #pragma unroll
    for (int dt = 0; dt < 8; dt++) {
        int d = dt * 16 + col15;
        #pragma unroll
        for (int r = 0; r < 4; r++) {
            int q = Q0 + w * 16 + quad * 4 + r;
            Yout[((size_t)(b * Tc + q)) * Ec + h * HDc + d] = (__bf16)(yacc[dt][r] * sc);
        }
    }
}

// ---------------- column reduce: embsum[b,e] += sum_t xf[b,t,e] ----------------
__global__ __launch_bounds__(256) void colreduce_k(const __bf16* xf, float* embsum) {
    int b = blockIdx.x, chunk = blockIdx.y, e = threadIdx.x;
    const __bf16* p = xf + ((size_t)(b * Tc + chunk * 128)) * Ec + e;
    float s = 0.f;
    #pragma unroll 8
    for (int t = 0; t < 128; t++) s += (float)p[(size_t)t * Ec];
    atomicAdd(&embsum[b * Ec + e], s);
}

// ---------------- final: emb, logits, losses, outputs — FLOAT32 output ----------------
__global__ __launch_bounds__(256) void final_k(const float* embsum, const float* Yt,
                                               const float* head_w, const float* head_b,
                                               float* out) {
    __shared__ float semb[2048];
    __shared__ float slog[1072];
    int tid = threadIdx.x;
    for (int i = tid; i < 2048; i += 256) semb[i] = embsum[i] * (1.f / 2048.f);
    __syncthreads();
    float part1 = 0.f;
    for (int idx = tid; idx < 1072; idx += 256) {
        int b = idx / M2c, n = idx - b * M2c;
        float acc = head_b[n];
        const float* wn = head_w + (size_t)n * Ec;
        const float* e = semb + b * Ec;
        #pragma unroll 8
        for (int k = 0; k < Ec; k++) acc += e[k] * wn[k];
        acc = fmaxf(acc, 0.f);
        slog[idx] = acc;
        float d = acc - Yt[idx];
        part1 += d * d;
    }
    float part3 = 0.f;
    for (int idx = tid; idx < 1024; idx += 256) {
        int b = idx >> 7, i = idx & 127;
        float d = semb[b * Ec + i] - semb[b * Ec + 128 + i];
        part3 += d * d;
    }
    #pragma unroll
    for (int o = 32; o; o >>= 1) { part1 += __shfl_xor(part1, o, 64); part3 += __shfl_xor(part3, o, 64); }
    __shared__ float r1[4], r3[4];
    int w = tid >> 6;
    if ((tid & 63) == 0) { r1[w] = part1; r3[w] = part3; }
    __syncthreads();
    float l1 = sqrtf((r1[0] + r1[1] + r1[2] + r1[3]) / 1072.f);
    float l3 = sqrtf((r3[0] + r3[1] + r3[2] + r3[3]) / 1024.f);
    for (int idx = tid; idx < 1024; idx += 256) {
        int b = idx >> 7, i = idx & 127;
        out[idx]        = semb[b * Ec + i];
        out[1024 + idx] = semb[b * Ec + 128 + i];
    }
    if (tid == 0) {
        out[2048] = 50.f * l1 + l3;
        out[2049] = l1;
        out[2050] = l3;
    }
    for (int idx = tid; idx < 1072; idx += 256) out[2051 + idx] = slog[idx];
}

extern "C" void kernel_launch(void* const* d_in, const int* in_sizes, int n_in,
                              void* d_out, int out_size, void* d_ws, size_t ws_size,
                              hipStream_t stream) {
    const float* X        = (const float*)d_in[0];
    const float* Yt       = (const float*)d_in[1];
    const float* wpe      = (const float*)d_in[2];
    const float* ln1_g    = (const float*)d_in[3];
    const float* ln1_b    = (const float*)d_in[4];
    const float* attn_w   = (const float*)d_in[5];
    const float* attn_b   = (const float*)d_in[6];
    const float* apw      = (const float*)d_in[7];
    const float* apb      = (const float*)d_in[8];
    const float* ln2_g    = (const float*)d_in[9];
    const float* ln2_b    = (const float*)d_in[10];
    const float* fcw      = (const float*)d_in[11];
    const float* fcb      = (const float*)d_in[12];
    const float* mpw      = (const float*)d_in[13];
    const float* mpb      = (const float*)d_in[14];
    const float* lnf_g    = (const float*)d_in[15];
    const float* lnf_b    = (const float*)d_in[16];
    const float* head_w   = (const float*)d_in[17];
    const float* head_b   = (const float*)d_in[18];

    char* ws = (char*)d_ws;
    float*  xres   = (float*)(ws + 0);                    // 16 MB, reused as x3
    float*  x2     = (float*)(ws + 16777216);             // 16 MB, reused as xf (bf16)
    __bf16* hb     = (__bf16*)(ws + 33554432);            // 8 MB, reused as Yout
    __bf16* Qb     = (__bf16*)(ws + 41943040);            // 8 MB
    __bf16* Kb     = (__bf16*)(ws + 50331648);            // 8 MB
    __bf16* Vb     = (__bf16*)(ws + 58720256);            // 8 MB, reused as h2
    __bf16* Vt     = (__bf16*)(ws + 67108864);            // 8 MB
    __bf16* fcout  = (__bf16*)(ws + 75497472);            // 16 MB
    __bf16* wb     = (__bf16*)(ws + 92274688);            // 1 MB converted weights
    float*  embsum = (float*)(ws + 93323264);             // 8 KB

    __bf16* Yout = hb;         // after qkv, h is dead
    __bf16* h2   = Vb;         // after transpose, Vb is dead
    float*  x3   = xres;       // after attnproj, xres is dead
    __bf16* xf   = (__bf16*)x2;// after mlpproj, x2 is dead

    __bf16* wqkv = wb;
    __bf16* wap  = wb + 196608;
    __bf16* wfc  = wb + 262144;
    __bf16* wmp  = wb + 393216;

    prep_k<<<2048, 256, 0, stream>>>(attn_w, apw, fcw, mpw, wb, embsum);
    embed_ln_k<<<Mrows, 256, 0, stream>>>(X, wpe, ln1_g, ln1_b, xres, hb);
    gemm_bt<0><<<dim3(6, 128), 256, 0, stream>>>(hb, wqkv, attn_b, 768, 256,
                                                 nullptr, nullptr, nullptr, Qb, Kb, Vb);
    transpose_v<<<dim3(32, 2, 16), 256, 0, stream>>>((const unsigned short*)Vb, (unsigned short*)Vt);
    attn_k<<<dim3(32, 16), 256, 0, stream>>>(Qb, Kb, Vt, Yout);
    gemm_bt<1><<<dim3(2, 128), 256, 0, stream>>>(Yout, wap, apb, 256, 256,
                                                 xres, x2, nullptr, nullptr, nullptr, nullptr);
    ln_k<<<Mrows, 256, 0, stream>>>(x2, ln2_g, ln2_b, h2, 0);
    gemm_bt<2><<<dim3(4, 128), 256, 0, stream>>>(h2, wfc, fcb, 512, 256,
                                                 nullptr, nullptr, fcout, nullptr, nullptr, nullptr);
    gemm_bt<3><<<dim3(2, 128), 256, 0, stream>>>(fcout, wmp, mpb, 256, 512,
                                                 x2, x3, nullptr, nullptr, nullptr, nullptr);
    ln_k<<<Mrows, 256, 0, stream>>>(x3, lnf_g, lnf_b, xf, 1);
    colreduce_k<<<dim3(8, 16), 256, 0, stream>>>(xf, embsum);
    final_k<<<1, 256, 0, stream>>>(embsum, Yt, head_w, head_b, (float*)d_out);
}

// Round 5
// 282.037 us; speedup vs baseline: 1.0521x; 1.0521x over previous
//
#include <hip/hip_runtime.h>
#include <hip/hip_bf16.h>

// Problem constants
#define Bc 8
#define Tc 2048
#define Ec 256
#define Hc 2
#define HDc 128
#define Mrows (Bc*Tc)          // 16384
#define M2c 134

using bfx8  = __attribute__((ext_vector_type(8))) __bf16;
using f32x4 = __attribute__((ext_vector_type(4))) float;

__device__ __forceinline__ void gll16(const __bf16* g, __bf16* lds) {
    __builtin_amdgcn_global_load_lds(
        (const __attribute__((address_space(1))) unsigned int*)g,
        (__attribute__((address_space(3))) unsigned int*)lds, 16, 0, 0);
}

// ---------------- prep: convert weights to bf16, zero embsum ----------------
__global__ __launch_bounds__(256) void prep_k(const float* attn_w, const float* apw,
                                              const float* fcw, const float* mpw,
                                              __bf16* wb, float* embsum) {
    int i = blockIdx.x * 256 + threadIdx.x;
    if (i < 2048) embsum[i] = 0.f;
    if (i < 196608)       wb[i] = (__bf16)attn_w[i];
    else if (i < 262144)  wb[i] = (__bf16)apw[i - 196608];
    else if (i < 393216)  wb[i] = (__bf16)fcw[i - 262144];
    else if (i < 524288)  wb[i] = (__bf16)mpw[i - 393216];
}

// ---------------- embed + relu + LN1 (xres now bf16) ----------------
__global__ __launch_bounds__(256) void embed_ln_k(const float* X, const float* wpe,
                                                  const float* g, const float* bb,
                                                  __bf16* xres, __bf16* hb) {
    int m = blockIdx.x;
    int t = m & (Tc - 1);
    int e = threadIdx.x;
    float v = X[(size_t)m * Ec + e] + wpe[(size_t)t * Ec + e] + wpe[(size_t)(t >= 1024) * Ec + e];
    v = fmaxf(v, 0.f);
    xres[(size_t)m * Ec + e] = (__bf16)v;
    float s1 = v, s2 = v * v;
    #pragma unroll
    for (int o = 32; o; o >>= 1) { s1 += __shfl_xor(s1, o, 64); s2 += __shfl_xor(s2, o, 64); }
    __shared__ float a1[4], a2[4];
    int w = threadIdx.x >> 6;
    if ((threadIdx.x & 63) == 0) { a1[w] = s1; a2[w] = s2; }
    __syncthreads();
    float m1 = (a1[0] + a1[1] + a1[2] + a1[3]) * (1.f / 256.f);
    float m2 = (a2[0] + a2[1] + a2[2] + a2[3]) * (1.f / 256.f);
    float r = rsqrtf(m2 - m1 * m1 + 1e-5f);
    hb[(size_t)m * Ec + e] = (__bf16)((v - m1) * r * g[e] + bb[e]);
}

// ---------------- B^T GEMM (128x128 tile): EPI 0 = qkv scatter, EPI 2 = fc relu ----------------
template <int EPI>
__global__ __launch_bounds__(256) void gemm_bt(const __bf16* __restrict__ A,
                                               const __bf16* __restrict__ Bw,
                                               const float* __restrict__ bias,
                                               int N, int K,
                                               __bf16* __restrict__ outb,
                                               __bf16* __restrict__ Qb,
                                               __bf16* __restrict__ Kb,
                                               __bf16* __restrict__ Vb) {
    __shared__ __bf16 As[128 * 64];
    __shared__ __bf16 Bs[128 * 64];
    const int tid = threadIdx.x, w = tid >> 6, l = tid & 63;
    const int m0 = blockIdx.y * 128, n0 = blockIdx.x * 128;
    const int wr = w >> 1, wc = w & 1;
    const int quad = l >> 4, col15 = l & 15;

    f32x4 acc[4][4];
    f32x4 zz = {0.f, 0.f, 0.f, 0.f};
    #pragma unroll
    for (int i = 0; i < 4; i++)
        #pragma unroll
        for (int j = 0; j < 4; j++) acc[i][j] = zz;

    const int lrow = l >> 3;
    const int pbs  = l & 7;

    for (int kb = 0; kb < K; kb += 64) {
        #pragma unroll
        for (int it = 0; it < 4; it++) {
            int chunk = w * 4 + it;
            int row = chunk * 8 + lrow;
            int lb = pbs ^ (row & 7);
            gll16(A  + (size_t)(m0 + row) * K + kb + lb * 8, As + chunk * 512);
            gll16(Bw + (size_t)(n0 + row) * K + kb + lb * 8, Bs + chunk * 512);
        }
        __syncthreads();
        #pragma unroll
        for (int ks = 0; ks < 2; ks++) {
            bfx8 af[4], bfr[4];
            #pragma unroll
            for (int rt = 0; rt < 4; rt++) {
                int row = wr * 64 + rt * 16 + col15;
                int pb = (ks * 4 + quad) ^ (row & 7);
                af[rt] = *(const bfx8*)(As + row * 64 + pb * 8);
            }
            #pragma unroll
            for (int ct = 0; ct < 4; ct++) {
                int row = wc * 64 + ct * 16 + col15;
                int pb = (ks * 4 + quad) ^ (row & 7);
                bfr[ct] = *(const bfx8*)(Bs + row * 64 + pb * 8);
            }
            #pragma unroll
            for (int rt = 0; rt < 4; rt++)
                #pragma unroll
                for (int ct = 0; ct < 4; ct++)
                    acc[rt][ct] = __builtin_amdgcn_mfma_f32_16x16x32_bf16(af[rt], bfr[ct], acc[rt][ct], 0, 0, 0);
        }
        __syncthreads();
    }

    #pragma unroll
    for (int rt = 0; rt < 4; rt++)
        #pragma unroll
        for (int ct = 0; ct < 4; ct++) {
            int mgb = m0 + wr * 64 + rt * 16 + quad * 4;
            int ng  = n0 + wc * 64 + ct * 16 + col15;
            float bsv = bias[ng];
            #pragma unroll
            for (int r = 0; r < 4; r++) {
                float val = acc[rt][ct][r] + bsv;
                int mg = mgb + r;
                if constexpr (EPI == 0) {
                    val = fmaxf(val, 0.f);
                    int sel = ng >> 8;
                    int hh = (ng >> 7) & 1;
                    int d = ng & 127;
                    int bb = mg >> 11, tt = mg & (Tc - 1);
                    size_t idx = ((size_t)((bb * 2 + hh) * Tc + tt)) * HDc + d;
                    __bf16 bv = (__bf16)val;
                    if (sel == 0) Qb[idx] = bv;
                    else if (sel == 1) Kb[idx] = bv;
                    else Vb[idx] = bv;
                } else {
                    outb[(size_t)mg * 512 + ng] = (__bf16)fmaxf(val, 0.f);
                }
            }
        }
}

// ---------------- transpose V -> Vt[bh][d][t] ----------------
__global__ __launch_bounds__(256) void transpose_v(const unsigned short* Vb, unsigned short* Vt) {
    __shared__ unsigned short tile[64][66];
    int kt = blockIdx.x, dt = blockIdx.y, bh = blockIdx.z;
    int tid = threadIdx.x;
    int k0 = kt * 64, d0 = dt * 64;
    int rr = tid >> 4, cc = (tid & 15) * 4;
    #pragma unroll
    for (int p = 0; p < 4; p++) {
        int k = p * 16 + rr;
        const unsigned short* src = Vb + ((size_t)(bh * Tc + k0 + k)) * HDc + d0 + cc;
        ushort4 vv = *(const ushort4*)src;
        tile[k][cc] = vv.x; tile[k][cc + 1] = vv.y; tile[k][cc + 2] = vv.z; tile[k][cc + 3] = vv.w;
    }
    __syncthreads();
    #pragma unroll
    for (int p = 0; p < 4; p++) {
        int d = p * 16 + rr;
        unsigned short* dst = Vt + ((size_t)(bh * HDc + d0 + d)) * Tc + k0 + cc;
        ushort4 ov;
        ov.x = tile[cc][d]; ov.y = tile[cc + 1][d]; ov.z = tile[cc + 2][d]; ov.w = tile[cc + 3][d];
        *(ushort4*)dst = ov;
    }
}

// ---------------- causal relu attention v2 ----------------
// 128 q-rows/block, 2 row-tiles/wave (2x LDS-read reuse), kt=64 key tiles.
// Every q-tile split into two key-range halves (uniform work): partials -> Y1/Y2.
__global__ __launch_bounds__(256) void attn2_k(const __bf16* __restrict__ Qb,
                                               const __bf16* __restrict__ Kb,
                                               const __bf16* __restrict__ Vt,
                                               __bf16* __restrict__ Y1,
                                               __bf16* __restrict__ Y2) {
    __shared__ __bf16 QS[128 * 128];   // 32KB: Q staging, then reused as S (128x64)
    __shared__ __bf16 Ks[64 * 128];    // 16KB
    __shared__ __bf16 Vts[128 * 64];   // 16KB
    __bf16* Ss = QS;
    int bx = blockIdx.x, bh = blockIdx.y;
    int qq = (bx + bh) & 31;           // scramble so co-resident blocks differ in weight
    int qb = qq >> 1, half = qq & 1;
    int tid = threadIdx.x, w = tid >> 6, l = tid & 63;
    int Q0 = qb * 128;
    int quad = l >> 4, col15 = l & 15;

    // ---- stage Q (128x128) into QS ----
    {
        int lrow = l >> 4, pbs = l & 15;
        #pragma unroll
        for (int it = 0; it < 8; it++) {
            int chunk = w * 8 + it;
            int row = chunk * 4 + lrow;
            int lb = pbs ^ (row & 7);
            gll16(Qb + ((size_t)(bh * Tc + Q0 + row)) * HDc + lb * 8, QS + chunk * 512);
        }
    }
    __syncthreads();
    bfx8 qf[2][4];
    #pragma unroll
    for (int rt = 0; rt < 2; rt++)
        #pragma unroll
        for (int ks = 0; ks < 4; ks++) {
            int row = w * 32 + rt * 16 + col15;
            int pb = (ks * 4 + quad) ^ (row & 7);
            qf[rt][ks] = *(const bfx8*)(QS + row * 128 + pb * 8);
        }

    f32x4 zz = {0.f, 0.f, 0.f, 0.f};
    f32x4 yacc[2][8];
    #pragma unroll
    for (int rt = 0; rt < 2; rt++)
        #pragma unroll
        for (int dt = 0; dt < 8; dt++) yacc[rt][dt] = zz;

    int tot = 2 * qb + 2;          // kt64 tiles in causal range
    int h0 = tot >> 1;             // = qb+1
    int kts = half ? h0 : 0;
    int kte = half ? tot : h0;

    for (int kt = kts; kt < kte; kt++) {
        __syncthreads();   // prior iter done reading Ks/Vts (Q-barrier covers first iter)
        {
            int lrowK = l >> 4, pbsK = l & 15;
            #pragma unroll
            for (int it = 0; it < 4; it++) {
                int chunk = w * 4 + it;
                int row = chunk * 4 + lrowK;
                int lb = pbsK ^ (row & 7);
                gll16(Kb + ((size_t)(bh * Tc + kt * 64 + row)) * HDc + lb * 8, Ks + chunk * 512);
            }
            int lrowV = l >> 3, pbsV = l & 7;
            #pragma unroll
            for (int it = 0; it < 4; it++) {
                int chunk = w * 4 + it;
                int row = chunk * 8 + lrowV;
                int lb = pbsV ^ (row & 7);
                gll16(Vt + ((size_t)(bh * HDc + row)) * Tc + kt * 64 + lb * 8, Vts + chunk * 512);
            }
        }
        __syncthreads();

        // ---- S = Q K^T : 32 q-rows per wave x 64 keys ----
        f32x4 sacc[2][4];
        #pragma unroll
        for (int rt = 0; rt < 2; rt++)
            #pragma unroll
            for (int ct = 0; ct < 4; ct++) sacc[rt][ct] = zz;
        #pragma unroll
        for (int ks = 0; ks < 4; ks++) {
            bfx8 kf[4];
            #pragma unroll
            for (int ct = 0; ct < 4; ct++) {
                int row = ct * 16 + col15;
                int pb = (ks * 4 + quad) ^ (row & 7);
                kf[ct] = *(const bfx8*)(Ks + row * 128 + pb * 8);
            }
            #pragma unroll
            for (int rt = 0; rt < 2; rt++)
                #pragma unroll
                for (int ct = 0; ct < 4; ct++)
                    sacc[rt][ct] = __builtin_amdgcn_mfma_f32_16x16x32_bf16(qf[rt][ks], kf[ct], sacc[rt][ct], 0, 0, 0);
        }

        // ---- mask + relu -> Ss (own rows; same-wave LDS ordering, no barrier) ----
        #pragma unroll
        for (int rt = 0; rt < 2; rt++)
            #pragma unroll
            for (int ct = 0; ct < 4; ct++) {
                int kl = ct * 16 + col15;
                int kg = kt * 64 + kl;
                int blk = kl >> 3, off = kl & 7;
                #pragma unroll
                for (int r = 0; r < 4; r++) {
                    int qlw = w * 32 + rt * 16 + quad * 4 + r;
                    int qg = Q0 + qlw;
                    float val = (kg <= qg) ? fmaxf(sacc[rt][ct][r], 0.f) : 0.f;
                    int pb = blk ^ (qlw & 7);
                    Ss[qlw * 64 + pb * 8 + off] = (__bf16)val;
                }
            }

        // ---- Y += S * V ----
        #pragma unroll
        for (int ks = 0; ks < 2; ks++) {
            bfx8 sf[2];
            #pragma unroll
            for (int rt = 0; rt < 2; rt++) {
                int row = w * 32 + rt * 16 + col15;
                int pb = (ks * 4 + quad) ^ (row & 7);
                sf[rt] = *(const bfx8*)(Ss + row * 64 + pb * 8);
            }
            #pragma unroll
            for (int dt = 0; dt < 8; dt++) {
                int row = dt * 16 + col15;
                int pb = (ks * 4 + quad) ^ (row & 7);
                bfx8 vf = *(const bfx8*)(Vts + row * 64 + pb * 8);
                #pragma unroll
                for (int rt = 0; rt < 2; rt++)
                    yacc[rt][dt] = __builtin_amdgcn_mfma_f32_16x16x32_bf16(sf[rt], vf, yacc[rt][dt], 0, 0, 0);
            }
        }
    }

    __bf16* Yp = half ? Y2 : Y1;
    int b = bh >> 1, h = bh & 1;
    const float sc = 0.08838834764831845f;  // 1/sqrt(128)
    #pragma unroll
    for (int rt = 0; rt < 2; rt++)
        #pragma unroll
        for (int dt = 0; dt < 8; dt++) {
            int d = dt * 16 + col15;
            #pragma unroll
            for (int r = 0; r < 4; r++) {
                int q = Q0 + w * 32 + rt * 16 + quad * 4 + r;
                Yp[((size_t)(b * Tc + q)) * Ec + h * HDc + d] = (__bf16)(yacc[rt][dt][r] * sc);
            }
        }
}

// ---------------- combine: Yout = Y1 + Y2 ----------------
__global__ __launch_bounds__(256) void combine_k(const __bf16* Y1, const __bf16* Y2, __bf16* Yout) {
    size_t i = ((size_t)blockIdx.x * 256 + threadIdx.x) * 8;
    bfx8 a = *(const bfx8*)(Y1 + i);
    bfx8 b = *(const bfx8*)(Y2 + i);
    bfx8 o;
    #pragma unroll
    for (int j = 0; j < 8; j++) o[j] = (__bf16)((float)a[j] + (float)b[j]);
    *(bfx8*)(Yout + i) = o;
}

// ---------------- fused GEMM (64x256 tile) + LN epilogue ----------------
// MODE 0: attnproj — x2 = resid + C + bias; out1 = bf16(x2); out2 = LN(x2; g,b)
// MODE 1: mlpproj  — x3 = relu(resid + C + bias); xf = relu(LN(x3; g,b));
//                    column-reduce xf into embsum (nothing else written)
template <int MODE>
__global__ __launch_bounds__(256) void gemm_ln(const __bf16* __restrict__ A,
                                               const __bf16* __restrict__ W,
                                               const float* __restrict__ bias, int K,
                                               const __bf16* __restrict__ resid,
                                               const float* __restrict__ g,
                                               const float* __restrict__ bb,
                                               __bf16* __restrict__ out1,
                                               __bf16* __restrict__ out2,
                                               float* __restrict__ embsum) {
    __shared__ __bf16 As[64 * 64];     // 8KB
    __shared__ __bf16 Bs[256 * 64];    // 32KB
    __shared__ float cs[256];
    const int tid = threadIdx.x, w = tid >> 6, l = tid & 63;
    const int m0 = blockIdx.x * 64;
    const int quad = l >> 4, col15 = l & 15;
    const int lrow = l >> 3, pbs = l & 7;

    f32x4 acc[16];
    f32x4 zz = {0.f, 0.f, 0.f, 0.f};
    #pragma unroll
    for (int i = 0; i < 16; i++) acc[i] = zz;
    if (MODE == 1) { cs[tid] = 0.f; }

    for (int kb = 0; kb < K; kb += 64) {
        __syncthreads();
        #pragma unroll
        for (int it = 0; it < 2; it++) {   // A: 8 chunks
            int chunk = w * 2 + it;
            int row = chunk * 8 + lrow;
            int lb = pbs ^ (row & 7);
            gll16(A + (size_t)(m0 + row) * K + kb + lb * 8, As + chunk * 512);
        }
        #pragma unroll
        for (int it = 0; it < 8; it++) {   // B: 32 chunks (all 256 n-rows)
            int chunk = w * 8 + it;
            int row = chunk * 8 + lrow;
            int lb = pbs ^ (row & 7);
            gll16(W + (size_t)row * K + kb + lb * 8, Bs + chunk * 512);
        }
        __syncthreads();
        #pragma unroll
        for (int ks = 0; ks < 2; ks++) {
            int arow = w * 16 + col15;
            int apb = (ks * 4 + quad) ^ (arow & 7);
            bfx8 af = *(const bfx8*)(As + arow * 64 + apb * 8);
            #pragma unroll
            for (int ct = 0; ct < 16; ct++) {
                int brow = ct * 16 + col15;
                int bpb = (ks * 4 + quad) ^ (brow & 7);
                bfx8 bf = *(const bfx8*)(Bs + brow * 64 + bpb * 8);
                acc[ct] = __builtin_amdgcn_mfma_f32_16x16x32_bf16(af, bf, acc[ct], 0, 0, 0);
            }
        }
    }
    __syncthreads();

    // epilogue: wave w owns rows m0 + w*16 + quad*4 + r  (full 256-wide rows in quad-group)
    float xv[16][4];
    #pragma unroll
    for (int ct = 0; ct < 16; ct++) {
        int ng = ct * 16 + col15;
        float bsv = bias[ng];
        #pragma unroll
        for (int r = 0; r < 4; r++) {
            int mg = m0 + w * 16 + quad * 4 + r;
            float v = acc[ct][r] + bsv + (float)resid[(size_t)mg * 256 + ng];
            if (MODE == 1) v = fmaxf(v, 0.f);
            xv[ct][r] = v;
        }
    }
    if (MODE == 0) {
        #pragma unroll
        for (int ct = 0; ct < 16; ct++) {
            int ng = ct * 16 + col15;
            #pragma unroll
            for (int r = 0; r < 4; r++) {
                int mg = m0 + w * 16 + quad * 4 + r;
                out1[(size_t)mg * 256 + ng] = (__bf16)xv[ct][r];
            }
        }
    }
    // row stats over the 16-lane quad-group
    float s1[4], s2[4];
    #pragma unroll
    for (int r = 0; r < 4; r++) {
        float a = 0.f, b2 = 0.f;
        #pragma unroll
        for (int ct = 0; ct < 16; ct++) { a += xv[ct][r]; b2 += xv[ct][r] * xv[ct][r]; }
        #pragma unroll
        for (int o = 1; o < 16; o <<= 1) { a += __shfl_xor(a, o, 64); b2 += __shfl_xor(b2, o, 64); }
        s1[r] = a; s2[r] = b2;
    }
    float colsum[16];
    #pragma unroll
    for (int ct = 0; ct < 16; ct++) colsum[ct] = 0.f;
    #pragma unroll
    for (int r = 0; r < 4; r++) {
        float mu = s1[r] * (1.f / 256.f);
        float var = s2[r] * (1.f / 256.f) - mu * mu;
        float rs = rsqrtf(var + 1e-5f);
        #pragma unroll
        for (int ct = 0; ct < 16; ct++) {
            int ng = ct * 16 + col15;
            float h = (xv[ct][r] - mu) * rs * g[ng] + bb[ng];
            if (MODE == 1) {
                colsum[ct] += fmaxf(h, 0.f);
            } else {
                int mg = m0 + w * 16 + quad * 4 + r;
                out2[(size_t)mg * 256 + ng] = (__bf16)h;
            }
        }
    }
    if (MODE == 1) {
        #pragma unroll
        for (int ct = 0; ct < 16; ct++) {
            colsum[ct] += __shfl_xor(colsum[ct], 16, 64);
            colsum[ct] += __shfl_xor(colsum[ct], 32, 64);
        }
        if (quad == 0) {
            #pragma unroll
            for (int ct = 0; ct < 16; ct++)
                atomicAdd(&cs[ct * 16 + col15], colsum[ct]);
        }
        __syncthreads();
        atomicAdd(&embsum[(m0 >> 11) * 256 + tid], cs[tid]);
    }
}

// ---------------- final: emb, logits, losses, outputs — FLOAT32 output ----------------
__global__ __launch_bounds__(256) void final_k(const float* embsum, const float* Yt,
                                               const float* head_w, const float* head_b,
                                               float* out) {
    __shared__ float semb[2048];
    __shared__ float slog[1072];
    int tid = threadIdx.x;
    for (int i = tid; i < 2048; i += 256) semb[i] = embsum[i] * (1.f / 2048.f);
    __syncthreads();
    float part1 = 0.f;
    for (int idx = tid; idx < 1072; idx += 256) {
        int b = idx / M2c, n = idx - b * M2c;
        float acc = head_b[n];
        const float* wn = head_w + (size_t)n * Ec;
        const float* e = semb + b * Ec;
        #pragma unroll 8
        for (int k = 0; k < Ec; k++) acc += e[k] * wn[k];
        acc = fmaxf(acc, 0.f);
        slog[idx] = acc;
        float d = acc - Yt[idx];
        part1 += d * d;
    }
    float part3 = 0.f;
    for (int idx = tid; idx < 1024; idx += 256) {
        int b = idx >> 7, i = idx & 127;
        float d = semb[b * Ec + i] - semb[b * Ec + 128 + i];
        part3 += d * d;
    }
    #pragma unroll
    for (int o = 32; o; o >>= 1) { part1 += __shfl_xor(part1, o, 64); part3 += __shfl_xor(part3, o, 64); }
    __shared__ float r1[4], r3[4];
    int w = tid >> 6;
    if ((tid & 63) == 0) { r1[w] = part1; r3[w] = part3; }
    __syncthreads();
    float l1 = sqrtf((r1[0] + r1[1] + r1[2] + r1[3]) / 1072.f);
    float l3 = sqrtf((r3[0] + r3[1] + r3[2] + r3[3]) / 1024.f);
    for (int idx = tid; idx < 1024; idx += 256) {
        int b = idx >> 7, i = idx & 127;
        out[idx]        = semb[b * Ec + i];
        out[1024 + idx] = semb[b * Ec + 128 + i];
    }
    if (tid == 0) {
        out[2048] = 50.f * l1 + l3;
        out[2049] = l1;
        out[2050] = l3;
    }
    for (int idx = tid; idx < 1072; idx += 256) out[2051 + idx] = slog[idx];
}

extern "C" void kernel_launch(void* const* d_in, const int* in_sizes, int n_in,
                              void* d_out, int out_size, void* d_ws, size_t ws_size,
                              hipStream_t stream) {
    const float* X        = (const float*)d_in[0];
    const float* Yt       = (const float*)d_in[1];
    const float* wpe      = (const float*)d_in[2];
    const float* ln1_g    = (const float*)d_in[3];
    const float* ln1_b    = (const float*)d_in[4];
    const float* attn_w   = (const float*)d_in[5];
    const float* attn_b   = (const float*)d_in[6];
    const float* apw      = (const float*)d_in[7];
    const float* apb      = (const float*)d_in[8];
    const float* ln2_g    = (const float*)d_in[9];
    const float* ln2_b    = (const float*)d_in[10];
    const float* fcw      = (const float*)d_in[11];
    const float* fcb      = (const float*)d_in[12];
    const float* mpw      = (const float*)d_in[13];
    const float* mpb      = (const float*)d_in[14];
    const float* lnf_g    = (const float*)d_in[15];
    const float* lnf_b    = (const float*)d_in[16];
    const float* head_w   = (const float*)d_in[17];
    const float* head_b   = (const float*)d_in[18];

    char* ws = (char*)d_ws;
    const size_t MB = 1048576;
    __bf16* xres   = (__bf16*)(ws + 0 * MB);    // 8 MB
    __bf16* hb     = (__bf16*)(ws + 8 * MB);    // 8 MB; later Yout
    __bf16* Qb     = (__bf16*)(ws + 16 * MB);   // 8 MB; later x2
    __bf16* Kb     = (__bf16*)(ws + 24 * MB);   // 8 MB; later h2
    __bf16* Vb     = (__bf16*)(ws + 32 * MB);   // 8 MB
    __bf16* Vt     = (__bf16*)(ws + 40 * MB);   // 8 MB
    __bf16* Y1     = (__bf16*)(ws + 48 * MB);   // 8 MB
    __bf16* Y2     = (__bf16*)(ws + 56 * MB);   // 8 MB
    __bf16* fcout  = (__bf16*)(ws + 64 * MB);   // 16 MB
    __bf16* wb     = (__bf16*)(ws + 80 * MB);   // 1 MB
    float*  embsum = (float*)(ws + 81 * MB);    // 8 KB

    __bf16* Yout = hb;     // hb dead after gemm0
    __bf16* x2   = Qb;     // Qb dead after attn
    __bf16* h2   = Kb;     // Kb dead after attn

    __bf16* wqkv = wb;
    __bf16* wap  = wb + 196608;
    __bf16* wfc  = wb + 262144;
    __bf16* wmp  = wb + 393216;

    prep_k<<<2048, 256, 0, stream>>>(attn_w, apw, fcw, mpw, wb, embsum);
    embed_ln_k<<<Mrows, 256, 0, stream>>>(X, wpe, ln1_g, ln1_b, xres, hb);
    gemm_bt<0><<<dim3(6, 128), 256, 0, stream>>>(hb, wqkv, attn_b, 768, 256,
                                                 nullptr, Qb, Kb, Vb);
    transpose_v<<<dim3(32, 2, 16), 256, 0, stream>>>((const unsigned short*)Vb, (unsigned short*)Vt);
    attn2_k<<<dim3(32, 16), 256, 0, stream>>>(Qb, Kb, Vt, Y1, Y2);
    combine_k<<<2048, 256, 0, stream>>>(Y1, Y2, Yout);
    gemm_ln<0><<<256, 256, 0, stream>>>(Yout, wap, apb, 256, xres, ln2_g, ln2_b,
                                        x2, h2, nullptr);
    gemm_bt<2><<<dim3(4, 128), 256, 0, stream>>>(h2, wfc, fcb, 512, 256,
                                                 fcout, nullptr, nullptr, nullptr);
    gemm_ln<1><<<256, 256, 0, stream>>>(fcout, wmp, mpb, 512, x2, lnf_g, lnf_b,
                                        nullptr, nullptr, embsum);
    final_k<<<1, 256, 0, stream>>>(embsum, Yt, head_w, head_b, (float*)d_out);
}